// Round 10
// baseline (412.500 us; speedup 1.0000x reference)
//
#include <hip/hip_runtime.h>
#include <hip/hip_bf16.h>
#include <math.h>

typedef __bf16 bf16_t;
typedef __attribute__((ext_vector_type(8))) __bf16 bx8;
typedef __attribute__((ext_vector_type(4))) __bf16 bx4;
typedef __attribute__((ext_vector_type(4))) float fx4;

#define DEV __device__ __forceinline__

// async global->LDS, 16B per lane. LDS dest must be wave-uniform base (HW adds lane*16).
DEV void async_copy16(void* lds, const void* g) {
    __builtin_amdgcn_global_load_lds(
        (const __attribute__((address_space(1))) unsigned int*)g,
        (__attribute__((address_space(3))) unsigned int*)lds, 16, 0, 0);
}

// ---------------------------------------------------------------- convert
__global__ void __launch_bounds__(256) cvt_bf16(const float* __restrict__ in,
                                                bf16_t* __restrict__ out, int n) {
    int i = (blockIdx.x * 256 + threadIdx.x) * 4;
    if (i + 3 < n) {
        float4 v = *(const float4*)(in + i);
        bx4 o = { (__bf16)v.x, (__bf16)v.y, (__bf16)v.z, (__bf16)v.w };
        *(bx4*)(out + i) = o;
    }
}

// ---------------------------------------------------------------- GEMM C = A[MxK] * B[NxK]^T
// m97 structure: 128x128 tile, BK=32, 4 waves in 2x2, 4x4 16x16x32 MFMA tiles per wave.
// r7 lesson: 256^2 tile here -> 384 blocks = 1.5 rounds (half-idle round 2), net loss.
// m99/m100 lesson (guide): explicit dbuf on this structure is neutral — leave as is.
template <bool BF16_OUT>
__global__ void __launch_bounds__(256, 2) gemm_bt(const bf16_t* __restrict__ A,
                                                  const bf16_t* __restrict__ B,
                                                  void* __restrict__ C,
                                                  int M, int N, int K) {
    __shared__ bf16_t As[128 * 32];   // [row][k] row-major, 64B rows (4 x 16B chunks)
    __shared__ bf16_t Bs[128 * 32];
    const int tid = threadIdx.x;
    const int w = tid >> 6, lane = tid & 63;
    const int ln = lane & 15, quad = lane >> 4;
    const int m0 = blockIdx.y * 128, n0 = blockIdx.x * 128;
    const int wm = (w >> 1) * 64, wn = (w & 1) * 64;

    fx4 acc[4][4];
#pragma unroll
    for (int i = 0; i < 4; ++i)
#pragma unroll
        for (int j = 0; j < 4; ++j) acc[i][j] = (fx4){0.f, 0.f, 0.f, 0.f};

    for (int k0 = 0; k0 < K; k0 += 32) {
#pragma unroll
        for (int call = 0; call < 2; ++call) {
            int c = w * 128 + call * 64 + lane;
            int row = c >> 2, kc = c & 3;
            async_copy16(As + (size_t)(w * 128 + call * 64) * 8,
                         A + (size_t)(m0 + row) * K + k0 + kc * 8);
            async_copy16(Bs + (size_t)(w * 128 + call * 64) * 8,
                         B + (size_t)(n0 + row) * K + k0 + kc * 8);
        }
        __syncthreads();

        bx8 af[4], bf[4];
#pragma unroll
        for (int i = 0; i < 4; ++i)
            af[i] = *(const bx8*)(As + (size_t)(wm + i * 16 + ln) * 32 + quad * 8);
#pragma unroll
        for (int j = 0; j < 4; ++j)
            bf[j] = *(const bx8*)(Bs + (size_t)(wn + j * 16 + ln) * 32 + quad * 8);
#pragma unroll
        for (int i = 0; i < 4; ++i)
#pragma unroll
            for (int j = 0; j < 4; ++j)
                acc[i][j] = __builtin_amdgcn_mfma_f32_16x16x32_bf16(af[i], bf[j], acc[i][j], 0, 0, 0);
        __syncthreads();
    }

#pragma unroll
    for (int i = 0; i < 4; ++i) {
        int mrow = m0 + wm + i * 16 + quad * 4;
#pragma unroll
        for (int j = 0; j < 4; ++j) {
            int ncol = n0 + wn + j * 16 + ln;
#pragma unroll
            for (int r = 0; r < 4; ++r) {
                if (BF16_OUT)
                    ((bf16_t*)C)[(size_t)(mrow + r) * N + ncol] = (__bf16)acc[i][j][r];
                else
                    ((float*)C)[(size_t)(mrow + r) * N + ncol] = acc[i][j][r];
            }
        }
    }
}

// ---------------------------------------------------------------- V transpose: [b,t,hd] -> [b,h,hd,t]
__global__ void __launch_bounds__(256) vtrans(const bf16_t* __restrict__ qkv,
                                              bf16_t* __restrict__ vt) {
    __shared__ bf16_t tile[64][65];
    const int tid = threadIdx.x;
    const int bh = blockIdx.z;
    const int b = bh >> 4, h = bh & 15;
    const int t0 = blockIdx.x * 64, hd0 = blockIdx.y * 64;
    const bf16_t* src = qkv + (size_t)(b * 2048 + t0) * 6144 + 4096 + h * 128 + hd0;
    const int rr = tid >> 6, cc = tid & 63;
#pragma unroll
    for (int i = 0; i < 16; ++i)
        tile[rr + i * 4][cc] = src[(size_t)(rr + i * 4) * 6144 + cc];
    __syncthreads();
    bf16_t* dst = vt + ((size_t)bh * 128 + hd0) * 2048 + t0;
#pragma unroll
    for (int i = 0; i < 16; ++i)
        dst[(size_t)(rr + i * 4) * 2048 + cc] = tile[cc][rr + i * 4];
}

// ---------------------------------------------------------------- flash attention
// grid: 512 blocks (XCD-remapped), block 256 = 4 waves. wave w: q rows [w*32, w*32+32).
// r10: KVBLK=64 + K/V DOUBLE-BUFFER + prefetch-during-compute.
//   Ks [2 buf][4 pl(hd)][64 t][32]   32 KB
//   Vs [2 buf][2 pl(t) ][128 hd][32] 32 KB
//   Ps [4 waves][2 pl(s)][32 m][32]  16 KB   -> exactly 80 KB = 2 blocks/CU.
// Per kt: STAGE(kt+1 -> buf^1) issued at TOP (loads overlap the whole ~2000cy compute),
// one __syncthreads() at END (its vmcnt drain is cheap: loads already landed).
// r6/r9 issued loads immediately before the wait -> latency fully exposed; this fixes it
// with plain __syncthreads semantics (no raw-barrier race risk, r8 lesson).
// Carried: plane-major conflict-free b128 reads (r4), no-max softmax + ones-MFMA lsum (r5),
// P quad-XOR swizzle (r5), XCD remap (r5).
__global__ void __launch_bounds__(256, 2) attn(const bf16_t* __restrict__ qkv,
                                               const bf16_t* __restrict__ vt,
                                               bf16_t* __restrict__ y) {
    __shared__ bf16_t Ks[2 * 8192];   // 32 KB
    __shared__ bf16_t Vs[2 * 8192];   // 32 KB
    __shared__ bf16_t Ps[4 * 2048];   // 16 KB, wave-private
    const int tid = threadIdx.x;
    const int w = tid >> 6, lane = tid & 63;
    const int ln = lane & 15, quad = lane >> 4;
    const int lin = blockIdx.x;
    const int slot = lin >> 3;
    const int bh = (lin & 7) + ((slot >> 4) << 3);
    const int qt = slot & 15;
    const int b = bh >> 4, h = bh & 15;
    const float CEXP = 0.08838834764831845f * 1.44269504088896340f;  // (1/sqrt(128))*log2(e)

    const bf16_t* Qb = qkv + (size_t)(b * 2048 + qt * 128) * 6144 + h * 128;
    const bf16_t* Kb = qkv + (size_t)(b * 2048) * 6144 + 2048 + h * 128;
    const bf16_t* Vb = vt + (size_t)bh * 128 * 2048;

    // Q A-fragments direct from global (A[m=lane&15][k=quad*8+j], m120-verified layout)
    bx8 qf[2][4];
#pragma unroll
    for (int i = 0; i < 2; ++i)
#pragma unroll
        for (int kk = 0; kk < 4; ++kk)
            qf[i][kk] = *(const bx8*)(Qb + (size_t)(w * 32 + i * 16 + ln) * 6144 + kk * 32 + quad * 8);

    const __bf16 one = (__bf16)1.0f;
    const bx8 ones = { one, one, one, one, one, one, one, one };

    fx4 o[2][8];
#pragma unroll
    for (int i = 0; i < 2; ++i)
#pragma unroll
        for (int j = 0; j < 8; ++j) o[i][j] = (fx4){0.f, 0.f, 0.f, 0.f};
    fx4 lsum[2];
#pragma unroll
    for (int i = 0; i < 2; ++i) lsum[i] = (fx4){0.f, 0.f, 0.f, 0.f};

    bf16_t* Pw = Ps + (size_t)w * 2048;

    // K staging: wave w fills hd-plane w of [64 t][32 hd]; chunk cp=call*64+lane:
    //   row = cp>>2 (0..63), piece = cp&3. Linear LDS dest, 64B-coalesced source.
    // V staging: chunks c = w*256+call*64+lane over [2 pl(t)][128 hd][32 t]:
    //   plane = w>>1, hd = (w&1)*64 + call*16 + (lane>>2), tp = lane&3.
#define STAGE(kt_, buf_)                                                                  \
    {                                                                                     \
        _Pragma("unroll") for (int call = 0; call < 4; ++call) {                          \
            int cp = call * 64 + lane;                                                    \
            int row = cp >> 2, piece = cp & 3;                                            \
            async_copy16(Ks + (size_t)(buf_) * 8192 + w * 2048 + call * 512,              \
                         Kb + (size_t)((kt_) * 64 + row) * 6144 + w * 32 + piece * 8);    \
            int hd = (w & 1) * 64 + call * 16 + (lane >> 2);                              \
            async_copy16(Vs + (size_t)(buf_) * 8192 + w * 2048 + call * 512,              \
                         Vb + (size_t)hd * 2048 + (kt_) * 64 + (w >> 1) * 32 +            \
                             (lane & 3) * 8);                                             \
        }                                                                                 \
    }

    STAGE(0, 0);
    __syncthreads();

    for (int kt = 0; kt < 32; ++kt) {
        const int cur = kt & 1;
        if (kt < 31) STAGE(kt + 1, cur ^ 1);   // prefetch overlaps the whole compute below

        const bf16_t* Kc = Ks + (size_t)cur * 8192;
        const bf16_t* Vc = Vs + (size_t)cur * 8192;

        // S = Q K^T : 32 rows x 64 cols per wave = 2x4 tiles, 4 k-steps (plane-major)
        fx4 s[2][4];
#pragma unroll
        for (int i = 0; i < 2; ++i)
#pragma unroll
            for (int j = 0; j < 4; ++j) s[i][j] = (fx4){0.f, 0.f, 0.f, 0.f};
#pragma unroll
        for (int kk = 0; kk < 4; ++kk) {
            bx8 kf[4];
#pragma unroll
            for (int j = 0; j < 4; ++j)
                kf[j] = *(const bx8*)(Kc + (size_t)kk * 2048 + (j * 16 + ln) * 32 + quad * 8);
#pragma unroll
            for (int i = 0; i < 2; ++i)
#pragma unroll
                for (int j = 0; j < 4; ++j)
                    s[i][j] = __builtin_amdgcn_mfma_f32_16x16x32_bf16(qf[i][kk], kf[j], s[i][j], 0, 0, 0);
        }

        // no-max softmax numerator + P write (wave-private, quad-XOR swizzled planes)
#pragma unroll
        for (int i = 0; i < 2; ++i)
#pragma unroll
            for (int j = 0; j < 4; ++j)
#pragma unroll
                for (int r = 0; r < 4; ++r) {
                    float p = exp2f(s[i][j][r] * CEXP);
                    int prow = i * 16 + quad * 4 + r;
                    Pw[(j >> 1) * 1024 + prow * 32 + (((j & 1) * 16 + ln) ^ (quad << 3))] =
                        (__bf16)p;
                }

        // O += P V, l += P 1 : k = s over 64, 2 k-planes (conflict-free reads)
#pragma unroll
        for (int kk = 0; kk < 2; ++kk) {
            bx8 pf[2], vf[8];
#pragma unroll
            for (int i = 0; i < 2; ++i)
                pf[i] = *(const bx8*)(Pw + (size_t)kk * 1024 + (i * 16 + ln) * 32 +
                                      ((quad ^ ((ln >> 2) & 3)) << 3));
#pragma unroll
            for (int j = 0; j < 8; ++j)
                vf[j] = *(const bx8*)(Vc + (size_t)kk * 4096 + (j * 16 + ln) * 32 + quad * 8);
#pragma unroll
            for (int i = 0; i < 2; ++i) {
#pragma unroll
                for (int j = 0; j < 8; ++j)
                    o[i][j] = __builtin_amdgcn_mfma_f32_16x16x32_bf16(pf[i], vf[j], o[i][j], 0, 0, 0);
                lsum[i] = __builtin_amdgcn_mfma_f32_16x16x32_bf16(pf[i], ones, lsum[i], 0, 0, 0);
            }
        }

        __syncthreads();  // buf[cur] reads done; prefetch (issued at top) drained cheaply
    }
#undef STAGE

    // epilogue: y[b,t,h*128+hd] bf16; l rowsum is in lsum C-layout (same rows as o)
#pragma unroll
    for (int i = 0; i < 2; ++i)
#pragma unroll
        for (int r = 0; r < 4; ++r) {
            float rl = 1.0f / lsum[i][r];
#pragma unroll
            for (int j = 0; j < 8; ++j) {
                int t = qt * 128 + w * 32 + i * 16 + quad * 4 + r;
                int col = h * 128 + j * 16 + ln;
                y[(size_t)(b * 2048 + t) * 2048 + col] = (__bf16)(o[i][j][r] * rl);
            }
        }
}

// ---------------------------------------------------------------- launch
extern "C" void kernel_launch(void* const* d_in, const int* in_sizes, int n_in,
                              void* d_out, int out_size, void* d_ws, size_t ws_size,
                              hipStream_t stream) {
    const float* x    = (const float*)d_in[0];
    const float* wqkv = (const float*)d_in[1];
    const float* wo   = (const float*)d_in[2];
    float* out = (float*)d_out;
    char* ws = (char*)d_ws;

    // workspace layout (112 MB total)
    bf16_t* Xb  = (bf16_t*)(ws);                          // 16 MB  (reused as Y after QKV GEMM)
    bf16_t* Wqb = (bf16_t*)(ws + (size_t)(16u << 20));    // 24 MB
    bf16_t* Wob = (bf16_t*)(ws + (size_t)(40u << 20));    //  8 MB
    bf16_t* QKV = (bf16_t*)(ws + (size_t)(48u << 20));    // 48 MB
    bf16_t* VT  = (bf16_t*)(ws + (size_t)(96u << 20));    // 16 MB
    bf16_t* Y   = Xb;

    cvt_bf16<<<8388608 / 1024, 256, 0, stream>>>(x, Xb, 8388608);
    cvt_bf16<<<12582912 / 1024, 256, 0, stream>>>(wqkv, Wqb, 12582912);
    cvt_bf16<<<4194304 / 1024, 256, 0, stream>>>(wo, Wob, 4194304);

    // QKV = X * Wqkv^T  [4096 x 6144]  — m97 kernel (1536 blocks = 3 exact rounds)
    gemm_bt<true><<<dim3(48, 32), 256, 0, stream>>>(Xb, Wqb, QKV, 4096, 6144, 2048);
    // V -> [b,h,hd,t]
    vtrans<<<dim3(32, 2, 32), 256, 0, stream>>>(QKV, VT);
    // flash attention -> Y [4096 x 2048] bf16  (1-D grid, XCD-remapped inside)
    attn<<<dim3(512), 256, 0, stream>>>(QKV, VT, Y);
    // out = Y * Wo^T  [4096 x 2048] fp32 — m97 kernel
    gemm_bt<false><<<dim3(16, 32), 256, 0, stream>>>(Y, Wob, out, 4096, 2048, 2048);
}

// Round 11
// 382.625 us; speedup vs baseline: 1.0781x; 1.0781x over previous
//
#include <hip/hip_runtime.h>
#include <hip/hip_bf16.h>
#include <math.h>

typedef __bf16 bf16_t;
typedef __attribute__((ext_vector_type(8))) __bf16 bx8;
typedef __attribute__((ext_vector_type(4))) __bf16 bx4;
typedef __attribute__((ext_vector_type(4))) float fx4;

#define DEV __device__ __forceinline__

// async global->LDS, 16B per lane. LDS dest must be wave-uniform base (HW adds lane*16).
DEV void async_copy16(void* lds, const void* g) {
    __builtin_amdgcn_global_load_lds(
        (const __attribute__((address_space(1))) unsigned int*)g,
        (__attribute__((address_space(3))) unsigned int*)lds, 16, 0, 0);
}

// ---------------------------------------------------------------- convert
__global__ void __launch_bounds__(256) cvt_bf16(const float* __restrict__ in,
                                                bf16_t* __restrict__ out, int n) {
    int i = (blockIdx.x * 256 + threadIdx.x) * 4;
    if (i + 3 < n) {
        float4 v = *(const float4*)(in + i);
        bx4 o = { (__bf16)v.x, (__bf16)v.y, (__bf16)v.z, (__bf16)v.w };
        *(bx4*)(out + i) = o;
    }
}

// ---------------------------------------------------------------- GEMM C = A[MxK] * B[NxK]^T
// r11: m97 structure with BK=64 (halves barrier-drain events: 32 iters, 32 MFMA/barrier).
// Plane-major LDS [2 kplanes][128 rows][32] (64B rows) keeps ds_read_b128 conflict-free
// AND the global_load_lds staging linear (identity c*8 = p*4096 + row*32 + piece*8).
// LDS 32 KB total -> still 2 blocks/CU. (r7: 256^2 tile loses to grid quantization here;
// m132: BK=128's 64KB LDS loses occupancy. BK=64 is the middle point.)
template <bool BF16_OUT>
__global__ void __launch_bounds__(256, 2) gemm_bt(const bf16_t* __restrict__ A,
                                                  const bf16_t* __restrict__ B,
                                                  void* __restrict__ C,
                                                  int M, int N, int K) {
    __shared__ bf16_t As[2 * 4096];   // 16 KB: kplane*4096 + row*32 + e
    __shared__ bf16_t Bs[2 * 4096];   // 16 KB
    const int tid = threadIdx.x;
    const int w = tid >> 6, lane = tid & 63;
    const int ln = lane & 15, quad = lane >> 4;
    const int m0 = blockIdx.y * 128, n0 = blockIdx.x * 128;
    const int wm = (w >> 1) * 64, wn = (w & 1) * 64;

    fx4 acc[4][4];
#pragma unroll
    for (int i = 0; i < 4; ++i)
#pragma unroll
        for (int j = 0; j < 4; ++j) acc[i][j] = (fx4){0.f, 0.f, 0.f, 0.f};

    for (int k0 = 0; k0 < K; k0 += 64) {
        // stage A,B [128 rows][64 k] as 1024 chunks each; wave w owns [w*256, w*256+256).
        // chunk c: kplane = c>>9, row = (c>>2)&127, piece = c&3. 4 lanes/row, 64B segments.
#pragma unroll
        for (int call = 0; call < 4; ++call) {
            int c = w * 256 + call * 64 + lane;
            int p = c >> 9, row = (c >> 2) & 127, piece = c & 3;
            async_copy16(As + (size_t)(w * 256 + call * 64) * 8,
                         A + (size_t)(m0 + row) * K + k0 + p * 32 + piece * 8);
            async_copy16(Bs + (size_t)(w * 256 + call * 64) * 8,
                         B + (size_t)(n0 + row) * K + k0 + p * 32 + piece * 8);
        }
        __syncthreads();

#pragma unroll
        for (int kk = 0; kk < 2; ++kk) {
            bx8 af[4], bf[4];
#pragma unroll
            for (int i = 0; i < 4; ++i)
                af[i] = *(const bx8*)(As + (size_t)kk * 4096 + (wm + i * 16 + ln) * 32 + quad * 8);
#pragma unroll
            for (int j = 0; j < 4; ++j)
                bf[j] = *(const bx8*)(Bs + (size_t)kk * 4096 + (wn + j * 16 + ln) * 32 + quad * 8);
#pragma unroll
            for (int i = 0; i < 4; ++i)
#pragma unroll
                for (int j = 0; j < 4; ++j)
                    acc[i][j] = __builtin_amdgcn_mfma_f32_16x16x32_bf16(af[i], bf[j], acc[i][j], 0, 0, 0);
        }
        __syncthreads();
    }

    // epilogue: C/D layout col=lane&15, row=quad*4+r (m89-verified)
#pragma unroll
    for (int i = 0; i < 4; ++i) {
        int mrow = m0 + wm + i * 16 + quad * 4;
#pragma unroll
        for (int j = 0; j < 4; ++j) {
            int ncol = n0 + wn + j * 16 + ln;
#pragma unroll
            for (int r = 0; r < 4; ++r) {
                if (BF16_OUT)
                    ((bf16_t*)C)[(size_t)(mrow + r) * N + ncol] = (__bf16)acc[i][j][r];
                else
                    ((float*)C)[(size_t)(mrow + r) * N + ncol] = acc[i][j][r];
            }
        }
    }
}

// ---------------------------------------------------------------- V transpose: [b,t,hd] -> [b,h,hd,t]
__global__ void __launch_bounds__(256) vtrans(const bf16_t* __restrict__ qkv,
                                              bf16_t* __restrict__ vt) {
    __shared__ bf16_t tile[64][65];
    const int tid = threadIdx.x;
    const int bh = blockIdx.z;
    const int b = bh >> 4, h = bh & 15;
    const int t0 = blockIdx.x * 64, hd0 = blockIdx.y * 64;
    const bf16_t* src = qkv + (size_t)(b * 2048 + t0) * 6144 + 4096 + h * 128 + hd0;
    const int rr = tid >> 6, cc = tid & 63;
#pragma unroll
    for (int i = 0; i < 16; ++i)
        tile[rr + i * 4][cc] = src[(size_t)(rr + i * 4) * 6144 + cc];
    __syncthreads();
    bf16_t* dst = vt + ((size_t)bh * 128 + hd0) * 2048 + t0;
#pragma unroll
    for (int i = 0; i < 16; ++i)
        dst[(size_t)(rr + i * 4) * 2048 + cc] = tile[cc][rr + i * 4];
}

// ---------------------------------------------------------------- flash attention (r9 form — best measured)
// grid: 512 blocks (XCD-remapped), block 256 = 4 waves. wave w: q rows [w*32, w*32+32).
// Plane-major LDS (conflict-free b128 reads); Ps wave-private 8 KB; 72 KB total = 2 blocks/CU.
// Per kt: 4 quarters {QK^T -> exp -> P-write -> PV plane q}; 2 barriers/kt.
// Carried: no-max softmax, lsum via ones-MFMA, P quad-XOR swizzle, XCD remap.
// r8/r10 lessons: staging-latency pipelining is neutral-to-negative here (KV L2-resident,
// FETCH 24 MB); attn is LDS/compute-bound. Keep the simple schedule.
__global__ void __launch_bounds__(256, 2) attn(const bf16_t* __restrict__ qkv,
                                               const bf16_t* __restrict__ vt,
                                               bf16_t* __restrict__ y) {
    __shared__ bf16_t Ks[128 * 128];   // 32 KB
    __shared__ bf16_t Vs[128 * 128];   // 32 KB
    __shared__ bf16_t Ps[4 * 1024];    //  8 KB: wave w -> Ps + w*1024 (32x32 quarter)
    const int tid = threadIdx.x;
    const int w = tid >> 6, lane = tid & 63;
    const int ln = lane & 15, quad = lane >> 4;
    const int lin = blockIdx.x;
    const int slot = lin >> 3;
    const int bh = (lin & 7) + ((slot >> 4) << 3);
    const int qt = slot & 15;
    const int b = bh >> 4, h = bh & 15;
    const float CEXP = 0.08838834764831845f * 1.44269504088896340f;  // (1/sqrt(128))*log2(e)

    const bf16_t* Qb = qkv + (size_t)(b * 2048 + qt * 128) * 6144 + h * 128;
    const bf16_t* Kb = qkv + (size_t)(b * 2048) * 6144 + 2048 + h * 128;
    const bf16_t* Vb = vt + (size_t)bh * 128 * 2048;

    bx8 qf[2][4];
#pragma unroll
    for (int i = 0; i < 2; ++i)
#pragma unroll
        for (int kk = 0; kk < 4; ++kk)
            qf[i][kk] = *(const bx8*)(Qb + (size_t)(w * 32 + i * 16 + ln) * 6144 + kk * 32 + quad * 8);

    const __bf16 one = (__bf16)1.0f;
    const bx8 ones = { one, one, one, one, one, one, one, one };

    fx4 o[2][8];
#pragma unroll
    for (int i = 0; i < 2; ++i)
#pragma unroll
        for (int j = 0; j < 8; ++j) o[i][j] = (fx4){0.f, 0.f, 0.f, 0.f};
    fx4 lsum[2];
#pragma unroll
    for (int i = 0; i < 2; ++i) lsum[i] = (fx4){0.f, 0.f, 0.f, 0.f};

    bf16_t* Pw = Ps + (size_t)w * 1024;

    for (int kt = 0; kt < 16; ++kt) {
#pragma unroll
        for (int call = 0; call < 8; ++call) {
            int cp = call * 64 + lane;
            int row = cp >> 2, piece = cp & 3;
            async_copy16(Ks + (size_t)w * 4096 + call * 512,
                         Kb + (size_t)(kt * 128 + row) * 6144 + w * 32 + piece * 8);
            async_copy16(Vs + (size_t)w * 4096 + call * 512,
                         Vb + (size_t)row * 2048 + kt * 128 + w * 32 + piece * 8);
        }
        __syncthreads();

#pragma unroll
        for (int q = 0; q < 4; ++q) {
            fx4 s[2][2];
#pragma unroll
            for (int i = 0; i < 2; ++i)
#pragma unroll
                for (int jj = 0; jj < 2; ++jj) s[i][jj] = (fx4){0.f, 0.f, 0.f, 0.f};
#pragma unroll
            for (int kk = 0; kk < 4; ++kk) {
                bx8 kf0 = *(const bx8*)(Ks + (size_t)kk * 4096 + ((2 * q) * 16 + ln) * 32 + quad * 8);
                bx8 kf1 = *(const bx8*)(Ks + (size_t)kk * 4096 + ((2 * q + 1) * 16 + ln) * 32 + quad * 8);
#pragma unroll
                for (int i = 0; i < 2; ++i) {
                    s[i][0] = __builtin_amdgcn_mfma_f32_16x16x32_bf16(qf[i][kk], kf0, s[i][0], 0, 0, 0);
                    s[i][1] = __builtin_amdgcn_mfma_f32_16x16x32_bf16(qf[i][kk], kf1, s[i][1], 0, 0, 0);
                }
            }

#pragma unroll
            for (int i = 0; i < 2; ++i)
#pragma unroll
                for (int jj = 0; jj < 2; ++jj)
#pragma unroll
                    for (int r = 0; r < 4; ++r) {
                        float p = exp2f(s[i][jj][r] * CEXP);
                        int prow = i * 16 + quad * 4 + r;
                        Pw[prow * 32 + ((jj * 16 + ln) ^ (quad << 3))] = (__bf16)p;
                    }

#pragma unroll
            for (int i = 0; i < 2; ++i) {
                bx8 pf = *(const bx8*)(Pw + (size_t)(i * 16 + ln) * 32 +
                                       ((quad ^ ((ln >> 2) & 3)) << 3));
#pragma unroll
                for (int j = 0; j < 8; ++j) {
                    bx8 vf = *(const bx8*)(Vs + (size_t)q * 4096 + (j * 16 + ln) * 32 + quad * 8);
                    o[i][j] = __builtin_amdgcn_mfma_f32_16x16x32_bf16(pf, vf, o[i][j], 0, 0, 0);
                }
                lsum[i] = __builtin_amdgcn_mfma_f32_16x16x32_bf16(pf, ones, lsum[i], 0, 0, 0);
            }
        }
        __syncthreads();
    }

#pragma unroll
    for (int i = 0; i < 2; ++i)
#pragma unroll
        for (int r = 0; r < 4; ++r) {
            float rl = 1.0f / lsum[i][r];
#pragma unroll
            for (int j = 0; j < 8; ++j) {
                int t = qt * 128 + w * 32 + i * 16 + quad * 4 + r;
                int col = h * 128 + j * 16 + ln;
                y[(size_t)(b * 2048 + t) * 2048 + col] = (__bf16)(o[i][j][r] * rl);
            }
        }
}

// ---------------------------------------------------------------- launch
extern "C" void kernel_launch(void* const* d_in, const int* in_sizes, int n_in,
                              void* d_out, int out_size, void* d_ws, size_t ws_size,
                              hipStream_t stream) {
    const float* x    = (const float*)d_in[0];
    const float* wqkv = (const float*)d_in[1];
    const float* wo   = (const float*)d_in[2];
    float* out = (float*)d_out;
    char* ws = (char*)d_ws;

    // workspace layout (112 MB total)
    bf16_t* Xb  = (bf16_t*)(ws);                          // 16 MB  (reused as Y after QKV GEMM)
    bf16_t* Wqb = (bf16_t*)(ws + (size_t)(16u << 20));    // 24 MB
    bf16_t* Wob = (bf16_t*)(ws + (size_t)(40u << 20));    //  8 MB
    bf16_t* QKV = (bf16_t*)(ws + (size_t)(48u << 20));    // 48 MB
    bf16_t* VT  = (bf16_t*)(ws + (size_t)(96u << 20));    // 16 MB
    bf16_t* Y   = Xb;

    cvt_bf16<<<8388608 / 1024, 256, 0, stream>>>(x, Xb, 8388608);
    cvt_bf16<<<12582912 / 1024, 256, 0, stream>>>(wqkv, Wqb, 12582912);
    cvt_bf16<<<4194304 / 1024, 256, 0, stream>>>(wo, Wob, 4194304);

    // QKV = X * Wqkv^T  [4096 x 6144]  — BK=64 m97 (1536 blocks = 3 exact rounds)
    gemm_bt<true><<<dim3(48, 32), 256, 0, stream>>>(Xb, Wqb, QKV, 4096, 6144, 2048);
    // V -> [b,h,hd,t]
    vtrans<<<dim3(32, 2, 32), 256, 0, stream>>>(QKV, VT);
    // flash attention -> Y [4096 x 2048] bf16  (1-D grid, XCD-remapped inside)
    attn<<<dim3(512), 256, 0, stream>>>(QKV, VT, Y);
    // out = Y * Wo^T  [4096 x 2048] fp32 — BK=64 m97
    gemm_bt<false><<<dim3(16, 32), 256, 0, stream>>>(Y, Wob, out, 4096, 2048, 2048);
}